// Round 16
// baseline (109.561 us; speedup 1.0000x reference)
//
#include <hip/hip_runtime.h>
#include <math.h>

#define N 4096
#define D 128
#define P 16
#define KK 2048                    // P*D
#define NTB 16                     // 256-wide tiles per dim
#define NBLK (NTB * NTB)           // full grid: 256 blocks = 1/CU
#define LCAPD 30000                // worklist capacity in aliased staging LDS
#define CAP (1u << 20)             // global worklist capacity (4 MB)
#define WIN 1.5e-3f                // > 1.1e-3 rigorous scaled-f16 bound
#define ZSCALE 256.0f              // 2^8, exact
#define OSCALE (1.0f / 16777216.0f * 16.0f)  // 2^-20, exact

typedef _Float16 half_t;
typedef __attribute__((ext_vector_type(8))) _Float16 f16x8;
typedef __attribute__((ext_vector_type(4))) float f32x4;
typedef __attribute__((address_space(1))) const unsigned int* gptr_t;
typedef __attribute__((address_space(3))) unsigned int* lptr_t;

#define MF(a, b, c) __builtin_amdgcn_mfma_f32_16x16x32_f16(a, b, c, 0, 0, 0)

// ---------------------------------------------------------------------------
// K1: fused norms (f64) + scaled f16 pack into TILED fragment-order layout.
// zb block (panel pn, k2 = 32-k index): 1024 pieces of 16B;
// piece(row r, chunk c) = r*4 + (c ^ ((r>>1)&3))  [swizzle pre-baked].
// (r11 kernel, verbatim — refcheck-proven.)
// ---------------------------------------------------------------------------
__global__ __launch_bounds__(256) void k_pack(const float* __restrict__ c,
                                              const float* __restrict__ w,
                                              double* __restrict__ rnorm,
                                              half_t* __restrict__ zb,
                                              unsigned* gcnt, unsigned* govf,
                                              int do_init) {
    int n = blockIdx.x, tid = threadIdx.x;
    if (do_init && n == 0 && tid == 0) { *gcnt = 0; *govf = 0; }
    int p = tid >> 4, d0 = (tid & 15) * 8;
    const float* cc = c + (size_t)n * D + d0;
    const float* ww = w + (size_t)p * D + d0;
    float cv[8], wv[8];
    *(float4*)&cv[0] = *(const float4*)&cc[0];
    *(float4*)&cv[4] = *(const float4*)&cc[4];
    *(float4*)&wv[0] = *(const float4*)&ww[0];
    *(float4*)&wv[4] = *(const float4*)&ww[4];
    double s = 0.0;
#pragma unroll
    for (int i = 0; i < 8; ++i) {
        double v = (double)cv[i] * (double)wv[i];
        s += v * v;
    }
#pragma unroll
    for (int o = 1; o < 16; o <<= 1) s += __shfl_xor(s, o, 64);
    double rn = 1.0 / fmax(sqrt(s), 1e-12);
    if ((tid & 15) == 0) rnorm[p * N + n] = rn;
    float rnf = (float)rn;
    f16x8 o8;
#pragma unroll
    for (int i = 0; i < 8; ++i) o8[i] = (half_t)(cv[i] * wv[i] * rnf * ZSCALE);

    int panel = n >> 8, rowin = n & 255;
    int k = p * 128 + d0;
    int k2 = k >> 5;
    int cch = (k >> 3) & 3;
    int piece = rowin * 4 + (cch ^ ((rowin >> 1) & 3));
    *(f16x8*)&zb[((size_t)(panel * 64 + k2) * 1024 + piece) * 8] = o8;
}

// ---------------------------------------------------------------------------
// K2: f16 MFMA GEMM out = Z Z^T / 16, fused mask + boundary worklist.
// 256x256 tile, BK=64, 8 waves (2Mx4N; wave tile 128x64), full grid.
// FAITHFUL 8-PHASE m201 SCHEDULE. Segments per K-step: Ak0,Bk0,Ak1,Bk1
// (16 KB each); one segment staged per phase, in the phase AFTER its
// predecessor's last read (race-free by phase end-barrier + lgkmcnt(0)).
// Each load gets 5-7 phases of flight. vmcnt(6) ONLY at phases 4 and 8
// (readiness for the buf-flip one phase later). Per phase: ds_reads issue
// pre-barrier (fly across rendezvous), lgkmcnt(0) post-barrier, 16 MFMA
// under setprio, end barrier. LDS 128 KB = 2 buf x 4 seg x 16 KB.
// ---------------------------------------------------------------------------
template <bool FUSED>
__global__ __launch_bounds__(512, 2) void k_gemm(const half_t* __restrict__ zb,
                                                 float* __restrict__ out,
                                                 unsigned* __restrict__ gcnt,
                                                 unsigned* __restrict__ govf,
                                                 unsigned* __restrict__ glist) {
    __shared__ __align__(16) half_t smbuf[2][4][8192];   // 128 KB
    __shared__ unsigned wl3[4];

    int tid = threadIdx.x;
    int lane = tid & 63, wid = tid >> 6;
    int wm = wid >> 2, wn = wid & 3;

    int braw = blockIdx.x;                               // XCD swizzle (256 = 8x32)
    int b = (braw & 7) * 32 + (braw >> 3);
    int bi = b >> 4, bj = b & 15;
    int n0 = bi * 256, m0 = bj * 256;

    int rl = lane & 15, kc = lane >> 4;

    f32x4 acc[8][4] = {};
    f16x8 af[4], bk0[4], bk1[4];

    auto STAGEH = [&](int bf, int seg, int pn, int k2) {  // one 16KB segment
#pragma unroll
        for (int l = 0; l < 2; ++l) {
            const half_t* src = zb + ((size_t)(pn * 64 + k2) * 8192
                                      + (size_t)(wid * 128 + l * 64 + lane) * 8);
            __builtin_amdgcn_global_load_lds(
                (gptr_t)src, (lptr_t)(&smbuf[bf][seg][(wid * 128 + l * 64) * 8]),
                16, 0, 0);
        }
    };

#define LDA4(BUF, SEG, H) {                                                    \
    _Pragma("unroll")                                                          \
    for (int f = 0; f < 4; ++f) {                                              \
        int r = wm * 128 + (H) * 64 + f * 16 + rl;                             \
        af[f] = *(const f16x8*)&smbuf[BUF][SEG][(r * 4 + (kc ^ ((r >> 1) & 3))) * 8]; } }
#define LDB4(BUF, SEG, BF) {                                                   \
    _Pragma("unroll")                                                          \
    for (int j = 0; j < 4; ++j) {                                              \
        int r = wn * 64 + j * 16 + rl;                                         \
        BF[j] = *(const f16x8*)&smbuf[BUF][SEG][(r * 4 + (kc ^ ((r >> 1) & 3))) * 8]; } }
#define MM(BF, HO) {                                                           \
    __builtin_amdgcn_s_setprio(1);                                             \
    _Pragma("unroll")                                                          \
    for (int f = 0; f < 4; ++f)                                                \
        _Pragma("unroll")                                                      \
        for (int j = 0; j < 4; ++j)                                            \
            acc[(HO) + f][j] = MF(af[f], BF[j], acc[(HO) + f][j]);             \
    __builtin_amdgcn_s_setprio(0); }
#define BAR  __builtin_amdgcn_sched_barrier(0); __builtin_amdgcn_s_barrier();  \
             __builtin_amdgcn_sched_barrier(0);
#define LGK0 asm volatile("s_waitcnt lgkmcnt(0)" ::: "memory");                \
             __builtin_amdgcn_sched_barrier(0);
#define VM6  asm volatile("s_waitcnt vmcnt(6)" ::: "memory");                  \
             __builtin_amdgcn_sched_barrier(0);
#define VM0  asm volatile("s_waitcnt vmcnt(0)" ::: "memory");                  \
             __builtin_amdgcn_sched_barrier(0);

    // prologue: K-step 0 fully + K-step 1 minus Ak1 (pattern-consistent)
    STAGEH(0, 0, bi, 0); STAGEH(0, 1, bj, 0); STAGEH(0, 2, bi, 1); STAGEH(0, 3, bj, 1);
    STAGEH(1, 0, bi, 2); STAGEH(1, 1, bj, 2); STAGEH(1, 3, bj, 3);
    VM6 BAR                                   // K-step 0 landed; 3 segs in flight

    for (int i = 0; i < 15; ++i) {
        int q = 4 * i;
        // ph1: K-step 2i (buf0), k0, A-rows 0-63 | stage Ak1(2i+1)
        LDA4(0, 0, 0) LDB4(0, 1, bk0)
        STAGEH(1, 2, bi, q + 3);
        BAR LGK0 MM(bk0, 0) BAR
        // ph2: k0, A-rows 64-127 | stage Bk0(2i+2)
        LDA4(0, 0, 1)
        STAGEH(0, 1, bj, q + 4);
        BAR LGK0 MM(bk0, 4) BAR
        // ph3: k1, A 0-63 | stage Ak0(2i+2)
        LDA4(0, 2, 0) LDB4(0, 3, bk1)
        STAGEH(0, 0, bi, q + 4);
        BAR LGK0 MM(bk1, 0) BAR
        // ph4: k1, A 64-127 | stage Bk1(2i+2) | vmcnt(6)
        LDA4(0, 2, 1)
        STAGEH(0, 3, bj, q + 5);
        VM6 BAR LGK0 MM(bk1, 4) BAR
        // ph5: K-step 2i+1 (buf1), k0, A 0-63 | stage Ak1(2i+2)
        LDA4(1, 0, 0) LDB4(1, 1, bk0)
        STAGEH(0, 2, bi, q + 5);
        BAR LGK0 MM(bk0, 0) BAR
        // ph6: k0, A 64-127 | stage Bk0(2i+3)
        LDA4(1, 0, 1)
        STAGEH(1, 1, bj, q + 6);
        BAR LGK0 MM(bk0, 4) BAR
        // ph7: k1, A 0-63 | stage Ak0(2i+3)
        LDA4(1, 2, 0) LDB4(1, 3, bk1)
        STAGEH(1, 0, bi, q + 6);
        BAR LGK0 MM(bk1, 0) BAR
        // ph8: k1, A 64-127 | stage Bk1(2i+3) | vmcnt(6)
        LDA4(1, 2, 1)
        STAGEH(1, 3, bj, q + 7);
        VM6 BAR LGK0 MM(bk1, 4) BAR
    }
    // peeled iter 15: K-steps 30 (buf0), 31 (buf1); only Ak1(31) left to stage
    LDA4(0, 0, 0) LDB4(0, 1, bk0)
    STAGEH(1, 2, bi, 63);
    BAR LGK0 MM(bk0, 0) BAR
    LDA4(0, 0, 1)
    BAR LGK0 MM(bk0, 4) BAR
    LDA4(0, 2, 0) LDB4(0, 3, bk1)
    BAR LGK0 MM(bk1, 0) BAR
    LDA4(0, 2, 1)
    VM0 BAR LGK0 MM(bk1, 4) BAR
    LDA4(1, 0, 0) LDB4(1, 1, bk0)
    BAR LGK0 MM(bk0, 0) BAR
    LDA4(1, 0, 1)
    BAR LGK0 MM(bk0, 4) BAR
    LDA4(1, 2, 0) LDB4(1, 3, bk1)
    BAR LGK0 MM(bk1, 0) BAR
    LDA4(1, 2, 1)
    BAR LGK0 MM(bk1, 4)

#undef LDA4
#undef LDB4
#undef MM
#undef BAR
#undef LGK0
#undef VM6
#undef VM0

    // staging LDS dead -> alias as worklist
    unsigned* lds_list = (unsigned*)&smbuf[0][0][0];
    __syncthreads();
    if (FUSED) {
        if (tid == 0) wl3[0] = 0;
        __syncthreads();
    }

#pragma unroll
    for (int fi = 0; fi < 8; ++fi)
#pragma unroll
        for (int fj = 0; fj < 4; ++fj) {
            int rbase = n0 + wm * 128 + fi * 16 + kc * 4;
            int ccol = m0 + wn * 64 + fj * 16 + rl;
#pragma unroll
            for (int q = 0; q < 4; ++q) {
                float a = acc[fi][fj][q] * OSCALE;
                float sv;
                if (FUSED) {
                    bool flg = fabsf(a - 0.1f) < WIN;
                    sv = flg ? a : (a > 0.1f ? a : 0.0f);
                    if (flg) {
                        unsigned pos = atomicAdd(&wl3[0], 1u);
                        if (pos < LCAPD)
                            lds_list[pos] = (unsigned)(rbase + q) | ((unsigned)ccol << 12);
                    }
                } else {
                    sv = a;
                }
                out[(size_t)(rbase + q) * N + ccol] = sv;
            }
        }

    if (FUSED) {
        __syncthreads();
        if (tid == 0) {
            unsigned tot = wl3[0];
            unsigned cnt = tot > LCAPD ? LCAPD : tot;
            wl3[2] = cnt;
            wl3[1] = atomicAdd(gcnt, cnt);
            if (tot > LCAPD) atomicOr(govf, 1u);
        }
        __syncthreads();
        unsigned cnt = wl3[2], base = wl3[1];
        for (unsigned e = tid; e < cnt; e += 512) {
            unsigned gi = base + e;
            if (gi < CAP) glist[gi] = lds_list[e];
            else atomicOr(govf, 1u);
        }
    }
}

// ---------------------------------------------------------------------------
// K3 (merged fix + guard): overflow -> full-pass resolve; else worklist-only.
// ---------------------------------------------------------------------------
__global__ __launch_bounds__(256) void k_fix3(const float* __restrict__ c,
                                              const float* __restrict__ w,
                                              const double* __restrict__ rnorm,
                                              const unsigned* __restrict__ gcnt,
                                              const unsigned* __restrict__ govf,
                                              const unsigned* __restrict__ glist,
                                              float* __restrict__ out) {
    __shared__ double w2[D * P];
    for (int e = threadIdx.x; e < P * D; e += 256) {
        int p = e >> 7, d = e & 127;
        double wv = (double)w[p * D + d];
        w2[d * P + p] = wv * wv;
    }
    __syncthreads();

    if (*govf) {
        size_t stride = (size_t)gridDim.x * 256;
        for (size_t idx = (size_t)blockIdx.x * 256 + threadIdx.x; idx < (size_t)N * N;
             idx += stride) {
            float a = out[idx];
            if (fabsf(a - 0.1f) >= WIN) {
                out[idx] = (a > 0.1f) ? a : 0.0f;
                continue;
            }
            int n = (int)(idx >> 12), m = (int)(idx & (N - 1));
            const float* cn = c + (size_t)n * D;
            const float* cm = c + (size_t)m * D;
            double acc[P];
#pragma unroll
            for (int p = 0; p < P; ++p) acc[p] = 0.0;
            for (int d0 = 0; d0 < D; d0 += 4) {
                float4 a4 = *(const float4*)&cn[d0];
                float4 b4 = *(const float4*)&cm[d0];
                float av[4] = {a4.x, a4.y, a4.z, a4.w};
                float bv[4] = {b4.x, b4.y, b4.z, b4.w};
#pragma unroll
                for (int q = 0; q < 4; ++q) {
                    double pr = (double)av[q] * (double)bv[q];
#pragma unroll
                    for (int p = 0; p < P; ++p) acc[p] += pr * w2[(d0 + q) * P + p];
                }
            }
            double t = 0.0;
#pragma unroll
            for (int p = 0; p < P; ++p)
                t += acc[p] * (rnorm[p * N + n] * rnorm[p * N + m]);
            double fin = t * 0.0625;
            out[idx] = (fin > 0.1) ? (float)fin : 0.0f;
        }
        return;
    }

    unsigned count = *gcnt;
    if (count > CAP) count = CAP;
    unsigned stride = gridDim.x * 256;
    for (unsigned e = blockIdx.x * 256 + threadIdx.x; e < count; e += stride) {
        unsigned u = glist[e];
        int n = u & 4095, m = (u >> 12) & 4095;
        const float* cn = c + (size_t)n * D;
        const float* cm = c + (size_t)m * D;
        double acc[P];
#pragma unroll
        for (int p = 0; p < P; ++p) acc[p] = 0.0;
        for (int d0 = 0; d0 < D; d0 += 4) {
            float4 a4 = *(const float4*)&cn[d0];
            float4 b4 = *(const float4*)&cm[d0];
            float av[4] = {a4.x, a4.y, a4.z, a4.w};
            float bv[4] = {b4.x, b4.y, b4.z, b4.w};
#pragma unroll
            for (int q = 0; q < 4; ++q) {
                double pr = (double)av[q] * (double)bv[q];
#pragma unroll
                for (int p = 0; p < P; ++p) acc[p] += pr * w2[(d0 + q) * P + p];
            }
        }
        double t = 0.0;
#pragma unroll
        for (int p = 0; p < P; ++p)
            t += acc[p] * (rnorm[p * N + n] * rnorm[p * N + m]);
        double fin = t * 0.0625;
        out[(size_t)n * N + m] = (fin > 0.1) ? (float)fin : 0.0f;
    }
}

// ---------------------------------------------------------------------------
// Fallback full-pass mask fix (only if ws too small; proven not taken).
// ---------------------------------------------------------------------------
__global__ __launch_bounds__(256) void k_fix_full(const float* __restrict__ c,
                                                  const float* __restrict__ w,
                                                  const double* __restrict__ rnorm,
                                                  float* __restrict__ out) {
    __shared__ double w2[D * P];
    for (int e = threadIdx.x; e < P * D; e += 256) {
        int p = e >> 7, d = e & 127;
        double wv = (double)w[p * D + d];
        w2[d * P + p] = wv * wv;
    }
    __syncthreads();
    size_t stride = (size_t)gridDim.x * 256;
    for (size_t idx = (size_t)blockIdx.x * 256 + threadIdx.x; idx < (size_t)N * N;
         idx += stride) {
        float a = out[idx];
        if (fabsf(a - 0.1f) >= WIN) {
            out[idx] = (a > 0.1f) ? a : 0.0f;
            continue;
        }
        int n = (int)(idx >> 12), m = (int)(idx & (N - 1));
        const float* cn = c + (size_t)n * D;
        const float* cm = c + (size_t)m * D;
        double acc[P];
#pragma unroll
        for (int p = 0; p < P; ++p) acc[p] = 0.0;
        for (int d0 = 0; d0 < D; d0 += 4) {
            float4 a4 = *(const float4*)&cn[d0];
            float4 b4 = *(const float4*)&cm[d0];
            float av[4] = {a4.x, a4.y, a4.z, a4.w};
            float bv[4] = {b4.x, b4.y, b4.z, b4.w};
#pragma unroll
            for (int q = 0; q < 4; ++q) {
                double pr = (double)av[q] * (double)bv[q];
#pragma unroll
                for (int p = 0; p < P; ++p) acc[p] += pr * w2[(d0 + q) * P + p];
            }
        }
        double t = 0.0;
#pragma unroll
        for (int p = 0; p < P; ++p)
            t += acc[p] * (rnorm[p * N + n] * rnorm[p * N + m]);
        double fin = t * 0.0625;
        out[idx] = (fin > 0.1) ? (float)fin : 0.0f;
    }
}

// ---------------------------------------------------------------------------
extern "C" void kernel_launch(void* const* d_in, const int* in_sizes, int n_in,
                              void* d_out, int out_size, void* d_ws, size_t ws_size,
                              hipStream_t stream) {
    const float* c = (const float*)d_in[0];
    const float* w = (const float*)d_in[1];
    float* out = (float*)d_out;
    char* ws = (char*)d_ws;

    double* rnorm = (double*)ws;                               // 512 KB
    size_t off = (size_t)P * N * 8;
    unsigned* gcnt = (unsigned*)(ws + off);
    unsigned* govf = gcnt + 1;
    unsigned* glist = (unsigned*)(ws + off + 128);             // 4 MB
    half_t* zb = (half_t*)(ws + off + 128 + (size_t)CAP * 4);  // 16 MB tiled
    size_t need = off + 128 + (size_t)CAP * 4 + (size_t)N * KK * 2;

    if (ws_size >= need) {
        k_pack<<<N, 256, 0, stream>>>(c, w, rnorm, zb, gcnt, govf, 1);
        k_gemm<true><<<NBLK, 512, 0, stream>>>(zb, out, gcnt, govf, glist);
        k_fix3<<<512, 256, 0, stream>>>(c, w, rnorm, gcnt, govf, glist, out);
    } else {
        half_t* zb2 = (half_t*)(ws + off);
        k_pack<<<N, 256, 0, stream>>>(c, w, rnorm, zb2, nullptr, nullptr, 0);
        k_gemm<false><<<NBLK, 512, 0, stream>>>(zb2, out, nullptr, nullptr, nullptr);
        k_fix_full<<<4096, 256, 0, stream>>>(c, w, rnorm, out);
    }
}

// Round 17
// 95.451 us; speedup vs baseline: 1.1478x; 1.1478x over previous
//
#include <hip/hip_runtime.h>
#include <math.h>

#define N 4096
#define D 128
#define P 16
#define KK 2048                    // P*D, single f16 plane
#define NT 32
#define NBLK (NT * (NT + 1) / 2)   // 528 upper-tri blocks
#define LCAP 2048                  // per-block LDS worklist (8 KB)
#define CAP (1u << 20)             // global worklist capacity (4 MB)
#define WIN 1.5e-3f                // > 1.1e-3 rigorous scaled-f16 bound
#define ZSCALE 256.0f              // 2^8, exact
#define OSCALE (1.0f / 16777216.0f * 16.0f)  // 0.0625 * 2^-16 = 2^-20, exact

typedef _Float16 half_t;
typedef __attribute__((ext_vector_type(8))) _Float16 f16x8;
typedef __attribute__((ext_vector_type(4))) float f32x4;
typedef __attribute__((address_space(1))) const unsigned int* gptr_t;
typedef __attribute__((address_space(3))) unsigned int* lptr_t;

// ---------------------------------------------------------------------------
// K1: fused norms (f64, cross-lane reduce) + scaled f16 pack + counter init.
// ---------------------------------------------------------------------------
__global__ __launch_bounds__(256) void k_pack(const float* __restrict__ c,
                                              const float* __restrict__ w,
                                              double* __restrict__ rnorm,
                                              half_t* __restrict__ zb,
                                              unsigned* gcnt, unsigned* govf,
                                              int do_init) {
    int n = blockIdx.x, tid = threadIdx.x;
    if (do_init && n == 0 && tid == 0) { *gcnt = 0; *govf = 0; }
    int p = tid >> 4, d0 = (tid & 15) * 8;
    const float* cc = c + (size_t)n * D + d0;
    const float* ww = w + (size_t)p * D + d0;
    float cv[8], wv[8];
    *(float4*)&cv[0] = *(const float4*)&cc[0];
    *(float4*)&cv[4] = *(const float4*)&cc[4];
    *(float4*)&wv[0] = *(const float4*)&ww[0];
    *(float4*)&wv[4] = *(const float4*)&ww[4];
    double s = 0.0;
#pragma unroll
    for (int i = 0; i < 8; ++i) {
        double v = (double)cv[i] * (double)wv[i];
        s += v * v;
    }
#pragma unroll
    for (int o = 1; o < 16; o <<= 1) s += __shfl_xor(s, o, 64);
    double rn = 1.0 / fmax(sqrt(s), 1e-12);
    if ((tid & 15) == 0) rnorm[p * N + n] = rn;
    float rnf = (float)rn;
    f16x8 o8;
#pragma unroll
    for (int i = 0; i < 8; ++i) o8[i] = (half_t)(cv[i] * wv[i] * rnf * ZSCALE);
    *(f16x8*)&zb[(size_t)n * KK + tid * 8] = o8;
}

// ---------------------------------------------------------------------------
// K2: f16 MFMA GEMM out = Z Z^T / 16, fused mask + boundary worklist.
// (measured best across 10 structural variants: 68 us)
// 128x128 tile, BK=32, 4 waves, double-buffered with COUNTED vmcnt:
//   STAGE(next) -> vmcnt(4) -> s_barrier -> ds_read+MFMA -> lgkmcnt(0)
//   -> s_barrier.  No vmcnt(0) in main loop.
// LDS swizzle sigma(row) = (row>>1)&3 on both stage-source and read.
// ---------------------------------------------------------------------------
template <bool FUSED>
__global__ __launch_bounds__(256, 4) void k_gemm(const half_t* __restrict__ zb,
                                                 float* __restrict__ out,
                                                 unsigned* __restrict__ gcnt,
                                                 unsigned* __restrict__ govf,
                                                 unsigned* __restrict__ glist) {
    __shared__ __align__(16) half_t As[2][128 * 32];
    __shared__ __align__(16) half_t Bs[2][128 * 32];
    __shared__ unsigned lds_list[LCAP];
    __shared__ unsigned lds_cnt, lds_base, lds_tot;

    int tid = threadIdx.x;
    if (FUSED && tid == 0) lds_cnt = 0;

    int lane = tid & 63, wv = tid >> 6;
    int wr = wv >> 1, wc = wv & 1;

    // XCD-chunked swizzle (528 = 8*66, bijective), then triangular decode
    int braw = blockIdx.x;
    int b = (braw & 7) * (NBLK / 8) + (braw >> 3);
    int ti = 0;
    while (b >= NT - ti) { b -= NT - ti; ++ti; }
    int tj = ti + b;
    int n0 = ti * 128, m0 = tj * 128;

    f32x4 acc[4][4] = {};
    int lrow = lane >> 2;                                  // staging row-in-slice
    int lchunk = (((lane & 3) ^ ((lrow >> 1) & 3)) * 8);   // swizzled source k-chunk

    auto STAGE = [&](int buf, int k0) {                    // 4 gload_lds per wave
#pragma unroll
        for (int h = 0; h < 2; ++h) {
            int s = h * 4 + wv;
            int row = s * 16 + lrow;
            __builtin_amdgcn_global_load_lds(
                (gptr_t)(zb + (size_t)(n0 + row) * KK + k0 + lchunk),
                (lptr_t)(&As[buf][s * 512]), 16, 0, 0);
            __builtin_amdgcn_global_load_lds(
                (gptr_t)(zb + (size_t)(m0 + row) * KK + k0 + lchunk),
                (lptr_t)(&Bs[buf][s * 512]), 16, 0, 0);
        }
    };

    int kk_c = lane >> 4;
    int rsel = lane & 15;
    int kphys = (kk_c ^ ((rsel >> 1) & 3)) * 8;            // swizzled read offset

    auto COMPUTE = [&](int cur) {
        f16x8 af[4], bfr[4];
#pragma unroll
        for (int f = 0; f < 4; ++f) {
            af[f]  = *(f16x8*)&As[cur][(wr * 64 + f * 16 + rsel) * 32 + kphys];
            bfr[f] = *(f16x8*)&Bs[cur][(wc * 64 + f * 16 + rsel) * 32 + kphys];
        }
#pragma unroll
        for (int i = 0; i < 4; ++i)
#pragma unroll
            for (int j = 0; j < 4; ++j)
                acc[i][j] = __builtin_amdgcn_mfma_f32_16x16x32_f16(af[i], bfr[j], acc[i][j], 0, 0, 0);
    };

    STAGE(0, 0);                       // prologue loads for buf0

#pragma unroll 2
    for (int t = 0; t < 63; ++t) {
        int cur = t & 1;
        STAGE(cur ^ 1, (t + 1) * 32);  // issue next tile (4 loads, stay in flight)
        asm volatile("s_waitcnt vmcnt(4)" ::: "memory");   // buf[cur] loads done
        __builtin_amdgcn_sched_barrier(0);
        __builtin_amdgcn_s_barrier();                      // all waves: buf[cur] ready
        __builtin_amdgcn_sched_barrier(0);
        COMPUTE(cur);
        asm volatile("s_waitcnt lgkmcnt(0)" ::: "memory"); // my ds_reads done
        __builtin_amdgcn_sched_barrier(0);
        __builtin_amdgcn_s_barrier();                      // reads done -> overwrite ok
        __builtin_amdgcn_sched_barrier(0);
    }
    // t = 63 (peeled): nothing left to stage; drain remaining loads fully.
    asm volatile("s_waitcnt vmcnt(0)" ::: "memory");
    __builtin_amdgcn_sched_barrier(0);
    __builtin_amdgcn_s_barrier();
    __builtin_amdgcn_sched_barrier(0);
    COMPUTE(1);

    int colD = lane & 15, rq = lane >> 4;
    bool mir = (ti != tj);
#pragma unroll
    for (int i = 0; i < 4; ++i)
#pragma unroll
        for (int j = 0; j < 4; ++j) {
            int rbase = n0 + wr * 64 + i * 16 + rq * 4;
            int ccol = m0 + wc * 64 + j * 16 + colD;
            float4 mv;
#pragma unroll
            for (int q = 0; q < 4; ++q) {
                float a = acc[i][j][q] * OSCALE;
                float sv;
                if (FUSED) {
                    bool flg = fabsf(a - 0.1f) < WIN;
                    sv = flg ? a : (a > 0.1f ? a : 0.0f);
                    if (flg) {
                        unsigned pos = atomicAdd(&lds_cnt, 1u);
                        unsigned ent = (unsigned)(rbase + q) | ((unsigned)ccol << 12) |
                                       (mir ? (1u << 24) : 0u);
                        if (pos < LCAP) lds_list[pos] = ent;
                    }
                } else {
                    sv = a;
                }
                out[(size_t)(rbase + q) * N + ccol] = sv;
                ((float*)&mv)[q] = sv;
            }
            if (mir) *(float4*)&out[(size_t)ccol * N + rbase] = mv;
        }

    if (FUSED) {
        __syncthreads();
        if (tid == 0) {
            unsigned tot = lds_cnt;
            unsigned cnt = tot > LCAP ? LCAP : tot;
            lds_tot = cnt;
            lds_base = atomicAdd(gcnt, cnt);
            if (tot > LCAP) atomicOr(govf, 1u);
        }
        __syncthreads();
        unsigned cnt = lds_tot, base = lds_base;
        for (unsigned e = tid; e < cnt; e += 256) {
            unsigned gi = base + e;
            if (gi < CAP) glist[gi] = lds_list[e];
            else atomicOr(govf, 1u);
        }
    }
}

// ---------------------------------------------------------------------------
// K3 (merged fix + guard): overflow -> full-pass resolve; else worklist-only.
// One entry per lane, 16 independent f64 accumulators, LDS-broadcast w^2.
// ---------------------------------------------------------------------------
__global__ __launch_bounds__(256) void k_fix3(const float* __restrict__ c,
                                              const float* __restrict__ w,
                                              const double* __restrict__ rnorm,
                                              const unsigned* __restrict__ gcnt,
                                              const unsigned* __restrict__ govf,
                                              const unsigned* __restrict__ glist,
                                              float* __restrict__ out) {
    __shared__ double w2[D * P];   // w2[d*16+p], 16 KB
    for (int e = threadIdx.x; e < P * D; e += 256) {
        int p = e >> 7, d = e & 127;
        double wv = (double)w[p * D + d];
        w2[d * P + p] = wv * wv;
    }
    __syncthreads();

    if (*govf) {
        size_t stride = (size_t)gridDim.x * 256;
        for (size_t idx = (size_t)blockIdx.x * 256 + threadIdx.x; idx < (size_t)N * N;
             idx += stride) {
            float a = out[idx];
            if (fabsf(a - 0.1f) >= WIN) {
                out[idx] = (a > 0.1f) ? a : 0.0f;
                continue;
            }
            int n = (int)(idx >> 12), m = (int)(idx & (N - 1));
            const float* cn = c + (size_t)n * D;
            const float* cm = c + (size_t)m * D;
            double acc[P];
#pragma unroll
            for (int p = 0; p < P; ++p) acc[p] = 0.0;
            for (int d0 = 0; d0 < D; d0 += 4) {
                float4 a4 = *(const float4*)&cn[d0];
                float4 b4 = *(const float4*)&cm[d0];
                float av[4] = {a4.x, a4.y, a4.z, a4.w};
                float bv[4] = {b4.x, b4.y, b4.z, b4.w};
#pragma unroll
                for (int q = 0; q < 4; ++q) {
                    double pr = (double)av[q] * (double)bv[q];
#pragma unroll
                    for (int p = 0; p < P; ++p) acc[p] += pr * w2[(d0 + q) * P + p];
                }
            }
            double t = 0.0;
#pragma unroll
            for (int p = 0; p < P; ++p)
                t += acc[p] * (rnorm[p * N + n] * rnorm[p * N + m]);
            double fin = t * 0.0625;
            out[idx] = (fin > 0.1) ? (float)fin : 0.0f;
        }
        return;
    }

    unsigned count = *gcnt;
    if (count > CAP) count = CAP;
    unsigned stride = gridDim.x * 256;
    for (unsigned e = blockIdx.x * 256 + threadIdx.x; e < count; e += stride) {
        unsigned u = glist[e];
        int n = u & 4095, m = (u >> 12) & 4095;
        const float* cn = c + (size_t)n * D;
        const float* cm = c + (size_t)m * D;
        double acc[P];
#pragma unroll
        for (int p = 0; p < P; ++p) acc[p] = 0.0;
        for (int d0 = 0; d0 < D; d0 += 4) {
            float4 a4 = *(const float4*)&cn[d0];
            float4 b4 = *(const float4*)&cm[d0];
            float av[4] = {a4.x, a4.y, a4.z, a4.w};
            float bv[4] = {b4.x, b4.y, b4.z, b4.w};
#pragma unroll
            for (int q = 0; q < 4; ++q) {
                double pr = (double)av[q] * (double)bv[q];
#pragma unroll
                for (int p = 0; p < P; ++p) acc[p] += pr * w2[(d0 + q) * P + p];
            }
        }
        double t = 0.0;
#pragma unroll
        for (int p = 0; p < P; ++p)
            t += acc[p] * (rnorm[p * N + n] * rnorm[p * N + m]);
        double fin = t * 0.0625;
        float res = (fin > 0.1) ? (float)fin : 0.0f;
        out[(size_t)n * N + m] = res;
        if (u >> 24) out[(size_t)m * N + n] = res;
    }
}

// ---------------------------------------------------------------------------
// Fallback full-pass mask fix (only if ws too small; proven not taken).
// ---------------------------------------------------------------------------
__global__ __launch_bounds__(256) void k_fix_full(const float* __restrict__ c,
                                                  const float* __restrict__ w,
                                                  const double* __restrict__ rnorm,
                                                  float* __restrict__ out) {
    __shared__ double w2[D * P];
    for (int e = threadIdx.x; e < P * D; e += 256) {
        int p = e >> 7, d = e & 127;
        double wv = (double)w[p * D + d];
        w2[d * P + p] = wv * wv;
    }
    __syncthreads();
    size_t stride = (size_t)gridDim.x * 256;
    for (size_t idx = (size_t)blockIdx.x * 256 + threadIdx.x; idx < (size_t)N * N;
         idx += stride) {
        float a = out[idx];
        if (fabsf(a - 0.1f) >= WIN) {
            out[idx] = (a > 0.1f) ? a : 0.0f;
            continue;
        }
        int n = (int)(idx >> 12), m = (int)(idx & (N - 1));
        const float* cn = c + (size_t)n * D;
        const float* cm = c + (size_t)m * D;
        double acc[P];
#pragma unroll
        for (int p = 0; p < P; ++p) acc[p] = 0.0;
        for (int d0 = 0; d0 < D; d0 += 4) {
            float4 a4 = *(const float4*)&cn[d0];
            float4 b4 = *(const float4*)&cm[d0];
            float av[4] = {a4.x, a4.y, a4.z, a4.w};
            float bv[4] = {b4.x, b4.y, b4.z, b4.w};
#pragma unroll
            for (int q = 0; q < 4; ++q) {
                double pr = (double)av[q] * (double)bv[q];
#pragma unroll
                for (int p = 0; p < P; ++p) acc[p] += pr * w2[(d0 + q) * P + p];
            }
        }
        double t = 0.0;
#pragma unroll
        for (int p = 0; p < P; ++p)
            t += acc[p] * (rnorm[p * N + n] * rnorm[p * N + m]);
        double fin = t * 0.0625;
        out[idx] = (fin > 0.1) ? (float)fin : 0.0f;
    }
}

// ---------------------------------------------------------------------------
extern "C" void kernel_launch(void* const* d_in, const int* in_sizes, int n_in,
                              void* d_out, int out_size, void* d_ws, size_t ws_size,
                              hipStream_t stream) {
    const float* c = (const float*)d_in[0];
    const float* w = (const float*)d_in[1];
    float* out = (float*)d_out;
    char* ws = (char*)d_ws;

    double* rnorm = (double*)ws;                               // 512 KB
    size_t off = (size_t)P * N * 8;
    unsigned* gcnt = (unsigned*)(ws + off);
    unsigned* govf = gcnt + 1;
    unsigned* glist = (unsigned*)(ws + off + 128);             // 4 MB
    half_t* zb = (half_t*)(ws + off + 128 + (size_t)CAP * 4);  // 16 MB
    size_t need = off + 128 + (size_t)CAP * 4 + (size_t)N * KK * 2;

    if (ws_size >= need) {
        k_pack<<<N, 256, 0, stream>>>(c, w, rnorm, zb, gcnt, govf, 1);
        k_gemm<true><<<NBLK, 256, 0, stream>>>(zb, out, gcnt, govf, glist);
        k_fix3<<<512, 256, 0, stream>>>(c, w, rnorm, gcnt, govf, glist, out);
    } else {
        half_t* zb2 = (half_t*)(ws + off);
        k_pack<<<N, 256, 0, stream>>>(c, w, rnorm, zb2, nullptr, nullptr, 0);
        k_gemm<false><<<NBLK, 256, 0, stream>>>(zb2, out, nullptr, nullptr, nullptr);
        k_fix_full<<<4096, 256, 0, stream>>>(c, w, rnorm, out);
    }
}